// Round 1
// baseline (815.433 us; speedup 1.0000x reference)
//
#include <hip/hip_runtime.h>
#include <math.h>

#define NEG_SLOPE 0.2f
#define CAP 64

// ---------------------------------------------------------------------------
// Tiled fp32 SGEMM: C[M,N] = A[M,K] @ B[K,N], row-major. BM=BN=64, BK=16,
// 256 threads, 4x4 micro-tile per thread. K must be a multiple of BK.
// ---------------------------------------------------------------------------
template<int BM, int BN, int BK, int TM, int TN>
__global__ __launch_bounds__(256) void sgemm_kernel(
    const float* __restrict__ A, const float* __restrict__ B,
    float* __restrict__ C, int M, int N, int K)
{
    __shared__ float As[BK][BM + 4];
    __shared__ float Bs[BK][BN + 4];
    const int tid = threadIdx.x;             // 0..255
    const int tx = tid % (BN / TN);          // 0..15
    const int ty = tid / (BN / TN);          // 0..15
    const int rowBase = blockIdx.y * BM;
    const int colBase = blockIdx.x * BN;

    float acc[TM][TN] = {};

    const int a_row = tid >> 2;              // 0..63
    const int a_col = (tid & 3) * 4;         // 0,4,8,12
    const int b_row = tid >> 4;              // 0..15
    const int b_col = (tid & 15) * 4;        // 0..60

    for (int k0 = 0; k0 < K; k0 += BK) {
        float4 av = make_float4(0.f, 0.f, 0.f, 0.f);
        int ar = rowBase + a_row;
        if (ar < M) av = *(const float4*)(A + (size_t)ar * K + k0 + a_col);
        As[a_col + 0][a_row] = av.x;
        As[a_col + 1][a_row] = av.y;
        As[a_col + 2][a_row] = av.z;
        As[a_col + 3][a_row] = av.w;

        float4 bv = make_float4(0.f, 0.f, 0.f, 0.f);
        int bc = colBase + b_col;
        if (bc + 3 < N) {
            bv = *(const float4*)(B + (size_t)(k0 + b_row) * N + bc);
        } else {
            float tmp[4] = {0.f, 0.f, 0.f, 0.f};
            for (int j = 0; j < 4; j++)
                if (bc + j < N) tmp[j] = B[(size_t)(k0 + b_row) * N + bc + j];
            bv = make_float4(tmp[0], tmp[1], tmp[2], tmp[3]);
        }
        *(float4*)&Bs[b_row][b_col] = bv;
        __syncthreads();

        #pragma unroll
        for (int kk = 0; kk < BK; kk++) {
            float a[TM], b[TN];
            *(float4*)a = *(const float4*)&As[kk][ty * TM];
            *(float4*)b = *(const float4*)&Bs[kk][tx * TN];
            #pragma unroll
            for (int i = 0; i < TM; i++)
                #pragma unroll
                for (int j = 0; j < TN; j++)
                    acc[i][j] = fmaf(a[i], b[j], acc[i][j]);
        }
        __syncthreads();
    }

    #pragma unroll
    for (int i = 0; i < TM; i++) {
        int r = rowBase + ty * TM + i;
        if (r >= M) continue;
        #pragma unroll
        for (int j = 0; j < TN; j++) {
            int c = colBase + tx * TN + j;
            if (c < N) C[(size_t)r * N + c] = acc[i][j];
        }
    }
}

// ---------------------------------------------------------------------------
// Per-node attention scores: s_src[n] = h[n,:] . a_src ; s_dst[n] = h . a_dst
// One wave (64 lanes) per node; 4 nodes per 256-thread block.
// ---------------------------------------------------------------------------
__global__ __launch_bounds__(256) void scores_kernel(
    const float* __restrict__ h, const float* __restrict__ a_src,
    const float* __restrict__ a_dst, float* __restrict__ s_src,
    float* __restrict__ s_dst, int N, int F)
{
    int n = blockIdx.x * 4 + (threadIdx.x >> 6);
    if (n >= N) return;
    int lane = threadIdx.x & 63;
    float ss = 0.f, sd = 0.f;
    for (int c = lane; c < F; c += 64) {
        float v = h[(size_t)n * F + c];
        ss += v * a_src[c];
        sd += v * a_dst[c];
    }
    for (int off = 32; off; off >>= 1) {
        ss += __shfl_xor(ss, off);
        sd += __shfl_xor(sd, off);
    }
    if (lane == 0) { s_src[n] = ss; s_dst[n] = sd; }
}

// ---------------------------------------------------------------------------
// CSR-by-dst with fixed per-node capacity (Poisson(16) degree; CAP=64 is
// ~20 sigma, overflow probability ~1e-20 so the guard never fires in practice)
// ---------------------------------------------------------------------------
__global__ void count_kernel(const int* __restrict__ ei, int* __restrict__ cnt,
                             int* __restrict__ csr, int E)
{
    int i = blockIdx.x * blockDim.x + threadIdx.x;
    if (i >= E) return;
    int s = ei[i];
    int d = ei[E + i];
    int pos = atomicAdd(&cnt[d], 1);
    if (pos < CAP) csr[(size_t)d * CAP + pos] = s;
}

__global__ void selfloop_kernel(int* __restrict__ cnt, int* __restrict__ csr, int N)
{
    int n = blockIdx.x * blockDim.x + threadIdx.x;
    if (n >= N) return;
    int pos = atomicAdd(&cnt[n], 1);
    if (pos < CAP) csr[(size_t)n * CAP + pos] = n;
}

// ---------------------------------------------------------------------------
// GAT aggregation: one wave per dst node. Pass 1: segment max of
// leaky_relu(s_src[src] + s_dst[n]). Pass 2: softmax-weighted sum of h[src].
// F==128: each lane owns cols {lane, lane+64}. F==40: lanes 0..39 own cols.
// Fused epilogue: bias + ReLU (layer 1) or bias + log_softmax (layer 2).
// ---------------------------------------------------------------------------
template<int F, bool RELU, bool LOGSOFTMAX>
__global__ __launch_bounds__(256) void agg_kernel(
    const float* __restrict__ h, const int* __restrict__ csr,
    const int* __restrict__ cnt, const float* __restrict__ s_src,
    const float* __restrict__ s_dst, const float* __restrict__ bias,
    float* __restrict__ out, int N)
{
    int n = blockIdx.x * 4 + (threadIdx.x >> 6);
    if (n >= N) return;
    int lane = threadIdx.x & 63;
    int deg = cnt[n]; if (deg > CAP) deg = CAP;
    const int* __restrict__ edges = csr + (size_t)n * CAP;
    float sdn = s_dst[n];

    // pass 1: segment max
    float m = -1e30f;
    for (int j = lane; j < deg; j += 64) {
        int s = edges[j];
        float e = s_src[s] + sdn;
        e = e > 0.f ? e : NEG_SLOPE * e;
        m = fmaxf(m, e);
    }
    for (int off = 32; off; off >>= 1) m = fmaxf(m, __shfl_xor(m, off));

    // pass 2: weighted aggregation (all lanes walk all edges; lanes own cols)
    float denom = 0.f;
    float acc0 = 0.f, acc1 = 0.f;
    for (int j = 0; j < deg; j++) {
        int s = edges[j];
        float e = s_src[s] + sdn;
        e = e > 0.f ? e : NEG_SLOPE * e;
        float w = __expf(e - m);
        denom += w;
        if (F == 128) {
            acc0 += w * h[(size_t)s * F + lane];
            acc1 += w * h[(size_t)s * F + 64 + lane];
        } else {
            if (lane < F) acc0 += w * h[(size_t)s * F + lane];
        }
    }
    float inv = 1.0f / denom;

    if (F == 128) {
        float v0 = acc0 * inv + bias[lane];
        float v1 = acc1 * inv + bias[64 + lane];
        if (RELU) { v0 = fmaxf(v0, 0.f); v1 = fmaxf(v1, 0.f); }
        out[(size_t)n * F + lane] = v0;
        out[(size_t)n * F + 64 + lane] = v1;
    } else {
        float v = (lane < F) ? (acc0 * inv + bias[lane]) : -1e30f;
        if (LOGSOFTMAX) {
            float mx = v;
            for (int off = 32; off; off >>= 1) mx = fmaxf(mx, __shfl_xor(mx, off));
            float ex = (lane < F) ? __expf(v - mx) : 0.f;
            float sum = ex;
            for (int off = 32; off; off >>= 1) sum += __shfl_xor(sum, off);
            v = v - mx - __logf(sum);
        }
        if (lane < F) out[(size_t)n * F + lane] = v;
    }
}

// ---------------------------------------------------------------------------
extern "C" void kernel_launch(void* const* d_in, const int* in_sizes, int n_in,
                              void* d_out, int out_size, void* d_ws, size_t ws_size,
                              hipStream_t stream)
{
    const float* x      = (const float*)d_in[0];   // [N, 256]
    const int*   ei     = (const int*)d_in[1];     // [2, E] (src row, dst row)
    const float* W1     = (const float*)d_in[2];   // [256, 128]
    const float* a_src1 = (const float*)d_in[3];   // [128]
    const float* a_dst1 = (const float*)d_in[4];   // [128]
    const float* b1     = (const float*)d_in[5];   // [128]
    const float* W2     = (const float*)d_in[6];   // [128, 40]
    const float* a_src2 = (const float*)d_in[7];   // [40]
    const float* a_dst2 = (const float*)d_in[8];   // [40]
    const float* b2     = (const float*)d_in[9];   // [40]
    float* out = (float*)d_out;                    // [N, 40]

    const int N = 100000;
    const int E = 1600000;

    // workspace layout
    char* ws = (char*)d_ws;
    size_t off = 0;
    auto alloc = [&](size_t bytes) -> void* {
        void* p = ws + off;
        off += (bytes + 255) & ~(size_t)255;
        return p;
    };
    float* h1   = (float*)alloc((size_t)N * 128 * 4);  // reused as h2 [N,40]
    float* out1 = (float*)alloc((size_t)N * 128 * 4);
    int*   csr  = (int*)alloc((size_t)N * CAP * 4);
    int*   cnt  = (int*)alloc((size_t)N * 4);
    float* ss1  = (float*)alloc((size_t)N * 4);
    float* sd1  = (float*)alloc((size_t)N * 4);
    float* ss2  = (float*)alloc((size_t)N * 4);
    float* sd2  = (float*)alloc((size_t)N * 4);

    hipMemsetAsync(cnt, 0, (size_t)N * 4, stream);

    // CSR build (graph identical for both layers)
    count_kernel<<<dim3((E + 255) / 256), dim3(256), 0, stream>>>(ei, cnt, csr, E);
    selfloop_kernel<<<dim3((N + 255) / 256), dim3(256), 0, stream>>>(cnt, csr, N);

    // ----- layer 1 -----
    dim3 g1((128 + 63) / 64, (N + 63) / 64);
    sgemm_kernel<64, 64, 16, 4, 4><<<g1, dim3(256), 0, stream>>>(x, W1, h1, N, 128, 256);
    scores_kernel<<<dim3((N + 3) / 4), dim3(256), 0, stream>>>(h1, a_src1, a_dst1, ss1, sd1, N, 128);
    agg_kernel<128, true, false><<<dim3((N + 3) / 4), dim3(256), 0, stream>>>(
        h1, csr, cnt, ss1, sd1, b1, out1, N);

    // ----- layer 2 -----
    float* h2 = h1;  // reuse (h1 dead after agg1)
    dim3 g2((40 + 63) / 64, (N + 63) / 64);
    sgemm_kernel<64, 64, 16, 4, 4><<<g2, dim3(256), 0, stream>>>(out1, W2, h2, N, 40, 128);
    scores_kernel<<<dim3((N + 3) / 4), dim3(256), 0, stream>>>(h2, a_src2, a_dst2, ss2, sd2, N, 40);
    agg_kernel<40, false, true><<<dim3((N + 3) / 4), dim3(256), 0, stream>>>(
        h2, csr, cnt, ss2, sd2, b2, out, N);
}

// Round 2
// 595.029 us; speedup vs baseline: 1.3704x; 1.3704x over previous
//
#include <hip/hip_runtime.h>
#include <math.h>

#define NEG_SLOPE 0.2f
#define CAP 64

// ---------------------------------------------------------------------------
// Tiled fp32 SGEMM: C[M,N] = A[M,K] @ B[K,N], row-major. BM=BN=64, BK=16,
// 256 threads, 4x4 micro-tile per thread. K must be a multiple of BK.
// ---------------------------------------------------------------------------
template<int BM, int BN, int BK, int TM, int TN>
__global__ __launch_bounds__(256) void sgemm_kernel(
    const float* __restrict__ A, const float* __restrict__ B,
    float* __restrict__ C, int M, int N, int K)
{
    __shared__ float As[BK][BM + 4];
    __shared__ float Bs[BK][BN + 4];
    const int tid = threadIdx.x;             // 0..255
    const int tx = tid % (BN / TN);          // 0..15
    const int ty = tid / (BN / TN);          // 0..15
    const int rowBase = blockIdx.y * BM;
    const int colBase = blockIdx.x * BN;

    float acc[TM][TN] = {};

    const int a_row = tid >> 2;              // 0..63
    const int a_col = (tid & 3) * 4;         // 0,4,8,12
    const int b_row = tid >> 4;              // 0..15
    const int b_col = (tid & 15) * 4;        // 0..60

    for (int k0 = 0; k0 < K; k0 += BK) {
        float4 av = make_float4(0.f, 0.f, 0.f, 0.f);
        int ar = rowBase + a_row;
        if (ar < M) av = *(const float4*)(A + (size_t)ar * K + k0 + a_col);
        As[a_col + 0][a_row] = av.x;
        As[a_col + 1][a_row] = av.y;
        As[a_col + 2][a_row] = av.z;
        As[a_col + 3][a_row] = av.w;

        float4 bv = make_float4(0.f, 0.f, 0.f, 0.f);
        int bc = colBase + b_col;
        if (bc + 3 < N) {
            bv = *(const float4*)(B + (size_t)(k0 + b_row) * N + bc);
        } else {
            float tmp[4] = {0.f, 0.f, 0.f, 0.f};
            for (int j = 0; j < 4; j++)
                if (bc + j < N) tmp[j] = B[(size_t)(k0 + b_row) * N + bc + j];
            bv = make_float4(tmp[0], tmp[1], tmp[2], tmp[3]);
        }
        *(float4*)&Bs[b_row][b_col] = bv;
        __syncthreads();

        #pragma unroll
        for (int kk = 0; kk < BK; kk++) {
            float a[TM], b[TN];
            *(float4*)a = *(const float4*)&As[kk][ty * TM];
            *(float4*)b = *(const float4*)&Bs[kk][tx * TN];
            #pragma unroll
            for (int i = 0; i < TM; i++)
                #pragma unroll
                for (int j = 0; j < TN; j++)
                    acc[i][j] = fmaf(a[i], b[j], acc[i][j]);
        }
        __syncthreads();
    }

    #pragma unroll
    for (int i = 0; i < TM; i++) {
        int r = rowBase + ty * TM + i;
        if (r >= M) continue;
        #pragma unroll
        for (int j = 0; j < TN; j++) {
            int c = colBase + tx * TN + j;
            if (c < N) C[(size_t)r * N + c] = acc[i][j];
        }
    }
}

// ---------------------------------------------------------------------------
// Per-node attention scores: s_src[n] = h[n,:] . a_src ; s_dst[n] = h . a_dst
// One wave (64 lanes) per node; 4 nodes per 256-thread block.
// ---------------------------------------------------------------------------
__global__ __launch_bounds__(256) void scores_kernel(
    const float* __restrict__ h, const float* __restrict__ a_src,
    const float* __restrict__ a_dst, float* __restrict__ s_src,
    float* __restrict__ s_dst, int N, int F)
{
    int n = blockIdx.x * 4 + (threadIdx.x >> 6);
    if (n >= N) return;
    int lane = threadIdx.x & 63;
    float ss = 0.f, sd = 0.f;
    for (int c = lane; c < F; c += 64) {
        float v = h[(size_t)n * F + c];
        ss += v * a_src[c];
        sd += v * a_dst[c];
    }
    for (int off = 32; off; off >>= 1) {
        ss += __shfl_xor(ss, off);
        sd += __shfl_xor(sd, off);
    }
    if (lane == 0) { s_src[n] = ss; s_dst[n] = sd; }
}

// ---------------------------------------------------------------------------
// CSR-by-dst with fixed per-node capacity (Poisson(16) degree; CAP=64 is
// ~20 sigma, overflow probability ~1e-20 so the guard never fires in practice)
// ---------------------------------------------------------------------------
__global__ void count_kernel(const int* __restrict__ ei, int* __restrict__ cnt,
                             int* __restrict__ csr, int E)
{
    int i = blockIdx.x * blockDim.x + threadIdx.x;
    if (i >= E) return;
    int s = ei[i];
    int d = ei[E + i];
    int pos = atomicAdd(&cnt[d], 1);
    if (pos < CAP) csr[(size_t)d * CAP + pos] = s;
}

__global__ void selfloop_kernel(int* __restrict__ cnt, int* __restrict__ csr, int N)
{
    int n = blockIdx.x * blockDim.x + threadIdx.x;
    if (n >= N) return;
    int pos = atomicAdd(&cnt[n], 1);
    if (pos < CAP) csr[(size_t)n * CAP + pos] = n;
}

// ---------------------------------------------------------------------------
// GAT aggregation: one wave per dst node (4 waves / block).
// Since deg <= CAP = 64, lane j owns edge j: its src index and softmax weight
// live in registers. The weighted-sum loop broadcasts (s, w) via __shfl (no
// memory dependency) so the only loads are independent coalesced h-gathers,
// unrolled 4x with separate accumulators for memory-level parallelism.
// F==128: lane owns float2 cols {2*lane, 2*lane+1}. F==40: lanes 0..39.
// Fused epilogue: bias + ReLU (layer 1) or bias + log_softmax (layer 2).
// ---------------------------------------------------------------------------
template<int F, bool RELU, bool LOGSOFTMAX>
__global__ __launch_bounds__(256) void agg_kernel(
    const float* __restrict__ h, const int* __restrict__ csr,
    const int* __restrict__ cnt, const float* __restrict__ s_src,
    const float* __restrict__ s_dst, const float* __restrict__ bias,
    float* __restrict__ out, int N)
{
    int n = blockIdx.x * 4 + (threadIdx.x >> 6);
    if (n >= N) return;
    int lane = threadIdx.x & 63;
    int deg = cnt[n]; if (deg > CAP) deg = CAP;
    const int* __restrict__ edges = csr + (size_t)n * CAP;
    float sdn = s_dst[n];

    // --- lane j owns edge j: load index + score, leaky_relu ---
    int   s_reg = (lane < deg) ? edges[lane] : 0;
    float e = (lane < deg) ? (s_src[s_reg] + sdn) : -1e30f;
    e = e > 0.f ? e : NEG_SLOPE * e;

    // wave max
    float m = e;
    #pragma unroll
    for (int off = 32; off; off >>= 1) m = fmaxf(m, __shfl_xor(m, off));

    // per-edge softmax weight + denom (self-loop guarantees denom > 0)
    float w_reg = (lane < deg) ? __expf(e - m) : 0.f;
    float denom = w_reg;
    #pragma unroll
    for (int off = 32; off; off >>= 1) denom += __shfl_xor(denom, off);
    float inv = 1.0f / denom;

    // --- weighted aggregation: broadcast (s, w) from owning lane ---
    if (F == 128) {
        const float2* __restrict__ hp = (const float2*)h;  // row stride 64
        float2 acc0 = {0.f, 0.f}, acc1 = {0.f, 0.f};
        float2 acc2 = {0.f, 0.f}, acc3 = {0.f, 0.f};
        int j = 0;
        for (; j + 3 < deg; j += 4) {
            int   s0 = __shfl(s_reg, j),     s1 = __shfl(s_reg, j + 1);
            int   s2 = __shfl(s_reg, j + 2), s3 = __shfl(s_reg, j + 3);
            float w0 = __shfl(w_reg, j),     w1 = __shfl(w_reg, j + 1);
            float w2 = __shfl(w_reg, j + 2), w3 = __shfl(w_reg, j + 3);
            float2 v0 = hp[(size_t)s0 * 64 + lane];
            float2 v1 = hp[(size_t)s1 * 64 + lane];
            float2 v2 = hp[(size_t)s2 * 64 + lane];
            float2 v3 = hp[(size_t)s3 * 64 + lane];
            acc0.x = fmaf(w0, v0.x, acc0.x); acc0.y = fmaf(w0, v0.y, acc0.y);
            acc1.x = fmaf(w1, v1.x, acc1.x); acc1.y = fmaf(w1, v1.y, acc1.y);
            acc2.x = fmaf(w2, v2.x, acc2.x); acc2.y = fmaf(w2, v2.y, acc2.y);
            acc3.x = fmaf(w3, v3.x, acc3.x); acc3.y = fmaf(w3, v3.y, acc3.y);
        }
        for (; j < deg; j++) {
            int   s0 = __shfl(s_reg, j);
            float w0 = __shfl(w_reg, j);
            float2 v0 = hp[(size_t)s0 * 64 + lane];
            acc0.x = fmaf(w0, v0.x, acc0.x); acc0.y = fmaf(w0, v0.y, acc0.y);
        }
        float rx = (acc0.x + acc1.x) + (acc2.x + acc3.x);
        float ry = (acc0.y + acc1.y) + (acc2.y + acc3.y);
        rx = rx * inv + bias[2 * lane];
        ry = ry * inv + bias[2 * lane + 1];
        if (RELU) { rx = fmaxf(rx, 0.f); ry = fmaxf(ry, 0.f); }
        float2 r = make_float2(rx, ry);
        ((float2*)out)[(size_t)n * 64 + lane] = r;
    } else {
        float acc0 = 0.f, acc1 = 0.f, acc2 = 0.f, acc3 = 0.f;
        int j = 0;
        for (; j + 3 < deg; j += 4) {
            int   s0 = __shfl(s_reg, j),     s1 = __shfl(s_reg, j + 1);
            int   s2 = __shfl(s_reg, j + 2), s3 = __shfl(s_reg, j + 3);
            float w0 = __shfl(w_reg, j),     w1 = __shfl(w_reg, j + 1);
            float w2 = __shfl(w_reg, j + 2), w3 = __shfl(w_reg, j + 3);
            float v0 = 0.f, v1 = 0.f, v2 = 0.f, v3 = 0.f;
            if (lane < F) {
                v0 = h[(size_t)s0 * F + lane];
                v1 = h[(size_t)s1 * F + lane];
                v2 = h[(size_t)s2 * F + lane];
                v3 = h[(size_t)s3 * F + lane];
            }
            acc0 = fmaf(w0, v0, acc0);
            acc1 = fmaf(w1, v1, acc1);
            acc2 = fmaf(w2, v2, acc2);
            acc3 = fmaf(w3, v3, acc3);
        }
        for (; j < deg; j++) {
            int   s0 = __shfl(s_reg, j);
            float w0 = __shfl(w_reg, j);
            float v0 = (lane < F) ? h[(size_t)s0 * F + lane] : 0.f;
            acc0 = fmaf(w0, v0, acc0);
        }
        float v = (acc0 + acc1) + (acc2 + acc3);
        v = (lane < F) ? (v * inv + bias[lane]) : -1e30f;
        if (LOGSOFTMAX) {
            float mx = v;
            #pragma unroll
            for (int off = 32; off; off >>= 1) mx = fmaxf(mx, __shfl_xor(mx, off));
            float ex = (lane < F) ? __expf(v - mx) : 0.f;
            float sum = ex;
            #pragma unroll
            for (int off = 32; off; off >>= 1) sum += __shfl_xor(sum, off);
            v = v - mx - __logf(sum);
        }
        if (lane < F) out[(size_t)n * F + lane] = v;
    }
}

// ---------------------------------------------------------------------------
extern "C" void kernel_launch(void* const* d_in, const int* in_sizes, int n_in,
                              void* d_out, int out_size, void* d_ws, size_t ws_size,
                              hipStream_t stream)
{
    const float* x      = (const float*)d_in[0];   // [N, 256]
    const int*   ei     = (const int*)d_in[1];     // [2, E] (src row, dst row)
    const float* W1     = (const float*)d_in[2];   // [256, 128]
    const float* a_src1 = (const float*)d_in[3];   // [128]
    const float* a_dst1 = (const float*)d_in[4];   // [128]
    const float* b1     = (const float*)d_in[5];   // [128]
    const float* W2     = (const float*)d_in[6];   // [128, 40]
    const float* a_src2 = (const float*)d_in[7];   // [40]
    const float* a_dst2 = (const float*)d_in[8];   // [40]
    const float* b2     = (const float*)d_in[9];   // [40]
    float* out = (float*)d_out;                    // [N, 40]

    const int N = 100000;
    const int E = 1600000;

    // workspace layout
    char* ws = (char*)d_ws;
    size_t off = 0;
    auto alloc = [&](size_t bytes) -> void* {
        void* p = ws + off;
        off += (bytes + 255) & ~(size_t)255;
        return p;
    };
    float* h1   = (float*)alloc((size_t)N * 128 * 4);  // reused as h2 [N,40]
    float* out1 = (float*)alloc((size_t)N * 128 * 4);
    int*   csr  = (int*)alloc((size_t)N * CAP * 4);
    int*   cnt  = (int*)alloc((size_t)N * 4);
    float* ss1  = (float*)alloc((size_t)N * 4);
    float* sd1  = (float*)alloc((size_t)N * 4);
    float* ss2  = (float*)alloc((size_t)N * 4);
    float* sd2  = (float*)alloc((size_t)N * 4);

    hipMemsetAsync(cnt, 0, (size_t)N * 4, stream);

    // CSR build (graph identical for both layers)
    count_kernel<<<dim3((E + 255) / 256), dim3(256), 0, stream>>>(ei, cnt, csr, E);
    selfloop_kernel<<<dim3((N + 255) / 256), dim3(256), 0, stream>>>(cnt, csr, N);

    // ----- layer 1 -----
    dim3 g1((128 + 63) / 64, (N + 63) / 64);
    sgemm_kernel<64, 64, 16, 4, 4><<<g1, dim3(256), 0, stream>>>(x, W1, h1, N, 128, 256);
    scores_kernel<<<dim3((N + 3) / 4), dim3(256), 0, stream>>>(h1, a_src1, a_dst1, ss1, sd1, N, 128);
    agg_kernel<128, true, false><<<dim3((N + 3) / 4), dim3(256), 0, stream>>>(
        h1, csr, cnt, ss1, sd1, b1, out1, N);

    // ----- layer 2 -----
    float* h2 = h1;  // reuse (h1 dead after agg1)
    dim3 g2((40 + 63) / 64, (N + 63) / 64);
    sgemm_kernel<64, 64, 16, 4, 4><<<g2, dim3(256), 0, stream>>>(out1, W2, h2, N, 40, 128);
    scores_kernel<<<dim3((N + 3) / 4), dim3(256), 0, stream>>>(h2, a_src2, a_dst2, ss2, sd2, N, 40);
    agg_kernel<40, false, true><<<dim3((N + 3) / 4), dim3(256), 0, stream>>>(
        h2, csr, cnt, ss2, sd2, b2, out, N);
}

// Round 3
// 573.591 us; speedup vs baseline: 1.4216x; 1.0374x over previous
//
#include <hip/hip_runtime.h>
#include <math.h>

#define NEG_SLOPE 0.2f
#define CAP 64

typedef __attribute__((ext_vector_type(8))) short short8;
typedef __attribute__((ext_vector_type(4))) short short4v;
typedef __attribute__((ext_vector_type(4))) float f32x4;

// fp32 -> bf16 with round-to-nearest-even
__device__ inline short f2bf(float f) {
    union { float f; unsigned u; } x; x.f = f;
    unsigned r = x.u + 0x7FFFu + ((x.u >> 16) & 1u);
    return (short)(r >> 16);
}

// ---------------------------------------------------------------------------
// Pre-swizzle W1 [256,128] fp32 -> bf16 B-fragments for mfma_f32_16x16x32_bf16.
// Fragment f = n_tile*8 + k_step; lane supplies B[k][n], n = n_tile*16 +
// (lane&15), k = k_step*32 + (lane>>4)*8 + j. Flat: bsw[(f*64+lane)*8 + j].
// ---------------------------------------------------------------------------
__global__ void pack_w1_kernel(const float* __restrict__ W1, short* __restrict__ bsw)
{
    int t = blockIdx.x * blockDim.x + threadIdx.x;   // 0..4095
    if (t >= 4096) return;
    int lane = t & 63;
    int f = t >> 6;            // 0..63
    int k_step = f & 7;
    int n_tile = f >> 3;
    int n  = n_tile * 16 + (lane & 15);
    int k0 = k_step * 32 + (lane >> 4) * 8;
    short8 v;
    #pragma unroll
    for (int j = 0; j < 8; j++)
        v[j] = f2bf(W1[(size_t)(k0 + j) * 128 + n]);
    ((short8*)bsw)[t] = v;
}

// ---------------------------------------------------------------------------
// GEMM1: h1[M,128] = x[M,256] @ W1  via bf16 MFMA, fp32 accumulate.
// Block = 256 threads (4 waves), 64 rows. x tile staged fp32->bf16 in LDS
// (row pad +8 bf16 to spread banks). Each wave: 16-row stripe, 8 A-frags in
// VGPRs reused over 8 n-tiles; B-frags stream from the L2-resident bsw.
// ---------------------------------------------------------------------------
__global__ __launch_bounds__(256) void gemm1_mfma_kernel(
    const float* __restrict__ x, const short* __restrict__ bsw,
    float* __restrict__ h1, int M)
{
    __shared__ short xs[64][264];
    const int tid = threadIdx.x;
    const int rowBase = blockIdx.x * 64;

    // stage 64x256 fp32 -> bf16 (each iteration: 4 rows, 1024 elems)
    #pragma unroll 4
    for (int i = 0; i < 16; i++) {
        int e = i * 1024 + tid * 4;
        int r = e >> 8, c = e & 255;
        int gr = rowBase + r;
        float4 v = make_float4(0.f, 0.f, 0.f, 0.f);
        if (gr < M) v = *(const float4*)(x + (size_t)gr * 256 + c);
        short4v s;
        s.x = f2bf(v.x); s.y = f2bf(v.y); s.z = f2bf(v.z); s.w = f2bf(v.w);
        *(short4v*)&xs[r][c] = s;
    }
    __syncthreads();

    const int wave = tid >> 6, lane = tid & 63;
    const int arow = wave * 16 + (lane & 15);
    const int acol0 = (lane >> 4) * 8;

    short8 a[8];
    #pragma unroll
    for (int k = 0; k < 8; k++)
        a[k] = *(const short8*)&xs[arow][k * 32 + acol0];

    const short8* __restrict__ bs = (const short8*)bsw;
    const int R0 = rowBase + wave * 16 + (lane >> 4) * 4;
    const int Cb = lane & 15;

    #pragma unroll
    for (int nt = 0; nt < 8; nt++) {
        f32x4 acc = {0.f, 0.f, 0.f, 0.f};
        #pragma unroll
        for (int k = 0; k < 8; k++) {
            short8 b = bs[(nt * 8 + k) * 64 + lane];
            acc = __builtin_amdgcn_mfma_f32_16x16x32_bf16(a[k], b, acc, 0, 0, 0);
        }
        int C = nt * 16 + Cb;
        #pragma unroll
        for (int r = 0; r < 4; r++) {
            int R = R0 + r;
            if (R < M) h1[(size_t)R * 128 + C] = acc[r];
        }
    }
}

// ---------------------------------------------------------------------------
// Tiled fp32 SGEMM (layer 2 only): C[M,N] = A[M,K] @ B[K,N].
// ---------------------------------------------------------------------------
template<int BM, int BN, int BK, int TM, int TN>
__global__ __launch_bounds__(256) void sgemm_kernel(
    const float* __restrict__ A, const float* __restrict__ B,
    float* __restrict__ C, int M, int N, int K)
{
    __shared__ float As[BK][BM + 4];
    __shared__ float Bs[BK][BN + 4];
    const int tid = threadIdx.x;
    const int tx = tid % (BN / TN);
    const int ty = tid / (BN / TN);
    const int rowBase = blockIdx.y * BM;
    const int colBase = blockIdx.x * BN;

    float acc[TM][TN] = {};

    const int a_row = tid >> 2;
    const int a_col = (tid & 3) * 4;
    const int b_row = tid >> 4;
    const int b_col = (tid & 15) * 4;

    for (int k0 = 0; k0 < K; k0 += BK) {
        float4 av = make_float4(0.f, 0.f, 0.f, 0.f);
        int ar = rowBase + a_row;
        if (ar < M) av = *(const float4*)(A + (size_t)ar * K + k0 + a_col);
        As[a_col + 0][a_row] = av.x;
        As[a_col + 1][a_row] = av.y;
        As[a_col + 2][a_row] = av.z;
        As[a_col + 3][a_row] = av.w;

        float4 bv = make_float4(0.f, 0.f, 0.f, 0.f);
        int bc = colBase + b_col;
        if (bc + 3 < N) {
            bv = *(const float4*)(B + (size_t)(k0 + b_row) * N + bc);
        } else {
            float tmp[4] = {0.f, 0.f, 0.f, 0.f};
            for (int j = 0; j < 4; j++)
                if (bc + j < N) tmp[j] = B[(size_t)(k0 + b_row) * N + bc + j];
            bv = make_float4(tmp[0], tmp[1], tmp[2], tmp[3]);
        }
        *(float4*)&Bs[b_row][b_col] = bv;
        __syncthreads();

        #pragma unroll
        for (int kk = 0; kk < BK; kk++) {
            float a[TM], b[TN];
            *(float4*)a = *(const float4*)&As[kk][ty * TM];
            *(float4*)b = *(const float4*)&Bs[kk][tx * TN];
            #pragma unroll
            for (int i = 0; i < TM; i++)
                #pragma unroll
                for (int j = 0; j < TN; j++)
                    acc[i][j] = fmaf(a[i], b[j], acc[i][j]);
        }
        __syncthreads();
    }

    #pragma unroll
    for (int i = 0; i < TM; i++) {
        int r = rowBase + ty * TM + i;
        if (r >= M) continue;
        #pragma unroll
        for (int j = 0; j < TN; j++) {
            int c = colBase + tx * TN + j;
            if (c < N) C[(size_t)r * N + c] = acc[i][j];
        }
    }
}

// ---------------------------------------------------------------------------
// Per-node attention scores: s_src[n] = h[n,:] . a_src ; s_dst[n] = h . a_dst
// ---------------------------------------------------------------------------
__global__ __launch_bounds__(256) void scores_kernel(
    const float* __restrict__ h, const float* __restrict__ a_src,
    const float* __restrict__ a_dst, float* __restrict__ s_src,
    float* __restrict__ s_dst, int N, int F)
{
    int n = blockIdx.x * 4 + (threadIdx.x >> 6);
    if (n >= N) return;
    int lane = threadIdx.x & 63;
    float ss = 0.f, sd = 0.f;
    for (int c = lane; c < F; c += 64) {
        float v = h[(size_t)n * F + c];
        ss += v * a_src[c];
        sd += v * a_dst[c];
    }
    for (int off = 32; off; off >>= 1) {
        ss += __shfl_xor(ss, off);
        sd += __shfl_xor(sd, off);
    }
    if (lane == 0) { s_src[n] = ss; s_dst[n] = sd; }
}

// ---------------------------------------------------------------------------
// CSR-by-dst with fixed per-node capacity (Poisson(16); CAP=64 ~20 sigma)
// ---------------------------------------------------------------------------
__global__ void count_kernel(const int* __restrict__ ei, int* __restrict__ cnt,
                             int* __restrict__ csr, int E)
{
    int i = blockIdx.x * blockDim.x + threadIdx.x;
    if (i >= E) return;
    int s = ei[i];
    int d = ei[E + i];
    int pos = atomicAdd(&cnt[d], 1);
    if (pos < CAP) csr[(size_t)d * CAP + pos] = s;
}

__global__ void selfloop_kernel(int* __restrict__ cnt, int* __restrict__ csr, int N)
{
    int n = blockIdx.x * blockDim.x + threadIdx.x;
    if (n >= N) return;
    int pos = atomicAdd(&cnt[n], 1);
    if (pos < CAP) csr[(size_t)n * CAP + pos] = n;
}

// ---------------------------------------------------------------------------
// GAT aggregation: one wave per dst node; lane j owns edge j (deg <= 64).
// Softmax state lives in registers; weighted sum broadcasts (s,w) via __shfl.
// ---------------------------------------------------------------------------
template<int F, bool RELU, bool LOGSOFTMAX>
__global__ __launch_bounds__(256) void agg_kernel(
    const float* __restrict__ h, const int* __restrict__ csr,
    const int* __restrict__ cnt, const float* __restrict__ s_src,
    const float* __restrict__ s_dst, const float* __restrict__ bias,
    float* __restrict__ out, int N)
{
    int n = blockIdx.x * 4 + (threadIdx.x >> 6);
    if (n >= N) return;
    int lane = threadIdx.x & 63;
    int deg = cnt[n]; if (deg > CAP) deg = CAP;
    const int* __restrict__ edges = csr + (size_t)n * CAP;
    float sdn = s_dst[n];

    int   s_reg = (lane < deg) ? edges[lane] : 0;
    float e = (lane < deg) ? (s_src[s_reg] + sdn) : -1e30f;
    e = e > 0.f ? e : NEG_SLOPE * e;

    float m = e;
    #pragma unroll
    for (int off = 32; off; off >>= 1) m = fmaxf(m, __shfl_xor(m, off));

    float w_reg = (lane < deg) ? __expf(e - m) : 0.f;
    float denom = w_reg;
    #pragma unroll
    for (int off = 32; off; off >>= 1) denom += __shfl_xor(denom, off);
    float inv = 1.0f / denom;

    if (F == 128) {
        const float2* __restrict__ hp = (const float2*)h;  // row stride 64
        float2 acc0 = {0.f, 0.f}, acc1 = {0.f, 0.f};
        float2 acc2 = {0.f, 0.f}, acc3 = {0.f, 0.f};
        int j = 0;
        for (; j + 3 < deg; j += 4) {
            int   s0 = __shfl(s_reg, j),     s1 = __shfl(s_reg, j + 1);
            int   s2 = __shfl(s_reg, j + 2), s3 = __shfl(s_reg, j + 3);
            float w0 = __shfl(w_reg, j),     w1 = __shfl(w_reg, j + 1);
            float w2 = __shfl(w_reg, j + 2), w3 = __shfl(w_reg, j + 3);
            float2 v0 = hp[(size_t)s0 * 64 + lane];
            float2 v1 = hp[(size_t)s1 * 64 + lane];
            float2 v2 = hp[(size_t)s2 * 64 + lane];
            float2 v3 = hp[(size_t)s3 * 64 + lane];
            acc0.x = fmaf(w0, v0.x, acc0.x); acc0.y = fmaf(w0, v0.y, acc0.y);
            acc1.x = fmaf(w1, v1.x, acc1.x); acc1.y = fmaf(w1, v1.y, acc1.y);
            acc2.x = fmaf(w2, v2.x, acc2.x); acc2.y = fmaf(w2, v2.y, acc2.y);
            acc3.x = fmaf(w3, v3.x, acc3.x); acc3.y = fmaf(w3, v3.y, acc3.y);
        }
        for (; j < deg; j++) {
            int   s0 = __shfl(s_reg, j);
            float w0 = __shfl(w_reg, j);
            float2 v0 = hp[(size_t)s0 * 64 + lane];
            acc0.x = fmaf(w0, v0.x, acc0.x); acc0.y = fmaf(w0, v0.y, acc0.y);
        }
        float rx = (acc0.x + acc1.x) + (acc2.x + acc3.x);
        float ry = (acc0.y + acc1.y) + (acc2.y + acc3.y);
        rx = rx * inv + bias[2 * lane];
        ry = ry * inv + bias[2 * lane + 1];
        if (RELU) { rx = fmaxf(rx, 0.f); ry = fmaxf(ry, 0.f); }
        ((float2*)out)[(size_t)n * 64 + lane] = make_float2(rx, ry);
    } else {
        float acc0 = 0.f, acc1 = 0.f, acc2 = 0.f, acc3 = 0.f;
        int j = 0;
        for (; j + 3 < deg; j += 4) {
            int   s0 = __shfl(s_reg, j),     s1 = __shfl(s_reg, j + 1);
            int   s2 = __shfl(s_reg, j + 2), s3 = __shfl(s_reg, j + 3);
            float w0 = __shfl(w_reg, j),     w1 = __shfl(w_reg, j + 1);
            float w2 = __shfl(w_reg, j + 2), w3 = __shfl(w_reg, j + 3);
            float v0 = 0.f, v1 = 0.f, v2 = 0.f, v3 = 0.f;
            if (lane < F) {
                v0 = h[(size_t)s0 * F + lane];
                v1 = h[(size_t)s1 * F + lane];
                v2 = h[(size_t)s2 * F + lane];
                v3 = h[(size_t)s3 * F + lane];
            }
            acc0 = fmaf(w0, v0, acc0);
            acc1 = fmaf(w1, v1, acc1);
            acc2 = fmaf(w2, v2, acc2);
            acc3 = fmaf(w3, v3, acc3);
        }
        for (; j < deg; j++) {
            int   s0 = __shfl(s_reg, j);
            float w0 = __shfl(w_reg, j);
            float v0 = (lane < F) ? h[(size_t)s0 * F + lane] : 0.f;
            acc0 = fmaf(w0, v0, acc0);
        }
        float v = (acc0 + acc1) + (acc2 + acc3);
        v = (lane < F) ? (v * inv + bias[lane]) : -1e30f;
        if (LOGSOFTMAX) {
            float mx = v;
            #pragma unroll
            for (int off = 32; off; off >>= 1) mx = fmaxf(mx, __shfl_xor(mx, off));
            float ex = (lane < F) ? __expf(v - mx) : 0.f;
            float sum = ex;
            #pragma unroll
            for (int off = 32; off; off >>= 1) sum += __shfl_xor(sum, off);
            v = v - mx - __logf(sum);
        }
        if (lane < F) out[(size_t)n * F + lane] = v;
    }
}

// ---------------------------------------------------------------------------
extern "C" void kernel_launch(void* const* d_in, const int* in_sizes, int n_in,
                              void* d_out, int out_size, void* d_ws, size_t ws_size,
                              hipStream_t stream)
{
    const float* x      = (const float*)d_in[0];   // [N, 256]
    const int*   ei     = (const int*)d_in[1];     // [2, E]
    const float* W1     = (const float*)d_in[2];   // [256, 128]
    const float* a_src1 = (const float*)d_in[3];
    const float* a_dst1 = (const float*)d_in[4];
    const float* b1     = (const float*)d_in[5];
    const float* W2     = (const float*)d_in[6];   // [128, 40]
    const float* a_src2 = (const float*)d_in[7];
    const float* a_dst2 = (const float*)d_in[8];
    const float* b2     = (const float*)d_in[9];
    float* out = (float*)d_out;                    // [N, 40]

    const int N = 100000;
    const int E = 1600000;

    char* ws = (char*)d_ws;
    size_t off = 0;
    auto alloc = [&](size_t bytes) -> void* {
        void* p = ws + off;
        off += (bytes + 255) & ~(size_t)255;
        return p;
    };
    float* h1   = (float*)alloc((size_t)N * 128 * 4);  // reused as h2 [N,40]
    float* out1 = (float*)alloc((size_t)N * 128 * 4);
    int*   csr  = (int*)alloc((size_t)N * CAP * 4);
    int*   cnt  = (int*)alloc((size_t)N * 4);
    float* ss1  = (float*)alloc((size_t)N * 4);
    float* sd1  = (float*)alloc((size_t)N * 4);
    float* ss2  = (float*)alloc((size_t)N * 4);
    float* sd2  = (float*)alloc((size_t)N * 4);
    short* bsw  = (short*)alloc((size_t)32768 * 2);    // swizzled bf16 W1

    hipMemsetAsync(cnt, 0, (size_t)N * 4, stream);

    // CSR build (graph identical for both layers)
    count_kernel<<<dim3((E + 255) / 256), dim3(256), 0, stream>>>(ei, cnt, csr, E);
    selfloop_kernel<<<dim3((N + 255) / 256), dim3(256), 0, stream>>>(cnt, csr, N);

    // ----- layer 1 -----
    pack_w1_kernel<<<dim3(16), dim3(256), 0, stream>>>(W1, bsw);
    gemm1_mfma_kernel<<<dim3((N + 63) / 64), dim3(256), 0, stream>>>(x, bsw, h1, N);
    scores_kernel<<<dim3((N + 3) / 4), dim3(256), 0, stream>>>(h1, a_src1, a_dst1, ss1, sd1, N, 128);
    agg_kernel<128, true, false><<<dim3((N + 3) / 4), dim3(256), 0, stream>>>(
        h1, csr, cnt, ss1, sd1, b1, out1, N);

    // ----- layer 2 -----
    float* h2 = h1;  // reuse (h1 dead after agg1)
    dim3 g2((40 + 63) / 64, (N + 63) / 64);
    sgemm_kernel<64, 64, 16, 4, 4><<<g2, dim3(256), 0, stream>>>(out1, W2, h2, N, 40, 128);
    scores_kernel<<<dim3((N + 3) / 4), dim3(256), 0, stream>>>(h2, a_src2, a_dst2, ss2, sd2, N, 40);
    agg_kernel<40, false, true><<<dim3((N + 3) / 4), dim3(256), 0, stream>>>(
        h2, csr, cnt, ss2, sd2, b2, out, N);
}

// Round 4
// 456.233 us; speedup vs baseline: 1.7873x; 1.2572x over previous
//
#include <hip/hip_runtime.h>
#include <math.h>

#define NEG_SLOPE 0.2f
#define CAP 64

typedef __attribute__((ext_vector_type(8))) short short8;
typedef __attribute__((ext_vector_type(4))) short short4v;
typedef __attribute__((ext_vector_type(4))) float f32x4;

// fp32 -> bf16 bits, round-to-nearest-even
__device__ inline unsigned short f2bf(float f) {
    union { float f; unsigned u; } x; x.f = f;
    unsigned r = x.u + 0x7FFFu + ((x.u >> 16) & 1u);
    return (unsigned short)(r >> 16);
}
__device__ inline float bfbits2f(unsigned u_shifted) {  // expects bits already in high half
    union { unsigned u; float f; } x; x.u = u_shifted; return x.f;
}

// ---------------------------------------------------------------------------
// Pack W1 [256,128] fp32 -> bf16 B-fragments for mfma_f32_16x16x32_bf16.
// frag f = n_tile*8 + k_step; lane gives B[k][n], n = n_tile*16+(lane&15),
// k = k_step*32 + (lane>>4)*8 + j. Flat: bsw[(f*64+lane)*8 + j].
// ---------------------------------------------------------------------------
__global__ void pack_w1_kernel(const float* __restrict__ W1, short* __restrict__ bsw)
{
    int t = blockIdx.x * blockDim.x + threadIdx.x;   // 0..4095
    if (t >= 4096) return;
    int lane = t & 63;
    int f = t >> 6;
    int k_step = f & 7;
    int n_tile = f >> 3;
    int n  = n_tile * 16 + (lane & 15);
    int k0 = k_step * 32 + (lane >> 4) * 8;
    short8 v;
    #pragma unroll
    for (int j = 0; j < 8; j++)
        v[j] = (short)f2bf(W1[(size_t)(k0 + j) * 128 + n]);
    ((short8*)bsw)[t] = v;
}

// W2 [128,40] -> 3 n-tiles (48 cols, zero-pad), 4 k-steps. 12 frags.
__global__ void pack_w2_kernel(const float* __restrict__ W2, short* __restrict__ bsw)
{
    int t = blockIdx.x * blockDim.x + threadIdx.x;   // 0..767
    if (t >= 768) return;
    int lane = t & 63;
    int f = t >> 6;            // 0..11
    int k_step = f & 3;
    int n_tile = f >> 2;
    int n  = n_tile * 16 + (lane & 15);
    int k0 = k_step * 32 + (lane >> 4) * 8;
    short8 v;
    #pragma unroll
    for (int j = 0; j < 8; j++)
        v[j] = (n < 40) ? (short)f2bf(W2[(size_t)(k0 + j) * 40 + n]) : (short)0;
    ((short8*)bsw)[t] = v;
}

// ---------------------------------------------------------------------------
// GEMM1: h1[M,128](bf16) = x[M,256] @ W1, bf16 MFMA, fp32 acc.
// Fused epilogue: s_src[n] = h[n,:].a_src, s_dst likewise (fp32 accumulators
// reduced across the 16 lanes sharing a row-quad).
// ---------------------------------------------------------------------------
__global__ __launch_bounds__(256) void gemm1_kernel(
    const float* __restrict__ x, const short* __restrict__ bsw,
    const float* __restrict__ a_src, const float* __restrict__ a_dst,
    unsigned short* __restrict__ h1, float* __restrict__ s_src,
    float* __restrict__ s_dst, int M)
{
    __shared__ short xs[64][264];
    const int tid = threadIdx.x;
    const int rowBase = blockIdx.x * 64;

    #pragma unroll 4
    for (int i = 0; i < 16; i++) {
        int e = i * 1024 + tid * 4;
        int r = e >> 8, c = e & 255;
        int gr = rowBase + r;
        float4 v = make_float4(0.f, 0.f, 0.f, 0.f);
        if (gr < M) v = *(const float4*)(x + (size_t)gr * 256 + c);
        short4v s;
        s.x = (short)f2bf(v.x); s.y = (short)f2bf(v.y);
        s.z = (short)f2bf(v.z); s.w = (short)f2bf(v.w);
        *(short4v*)&xs[r][c] = s;
    }
    __syncthreads();

    const int wave = tid >> 6, lane = tid & 63;
    const int arow = wave * 16 + (lane & 15);
    const int acol0 = (lane >> 4) * 8;

    short8 a[8];
    #pragma unroll
    for (int k = 0; k < 8; k++)
        a[k] = *(const short8*)&xs[arow][k * 32 + acol0];

    const short8* __restrict__ bs = (const short8*)bsw;
    const int R0 = rowBase + wave * 16 + (lane >> 4) * 4;
    const int Cb = lane & 15;

    float ss[4] = {0.f, 0.f, 0.f, 0.f};
    float sd[4] = {0.f, 0.f, 0.f, 0.f};

    #pragma unroll
    for (int nt = 0; nt < 8; nt++) {
        f32x4 acc = {0.f, 0.f, 0.f, 0.f};
        #pragma unroll
        for (int k = 0; k < 8; k++) {
            short8 b = bs[(nt * 8 + k) * 64 + lane];
            acc = __builtin_amdgcn_mfma_f32_16x16x32_bf16(a[k], b, acc, 0, 0, 0);
        }
        int C = nt * 16 + Cb;
        float as_ = a_src[C], ad_ = a_dst[C];
        #pragma unroll
        for (int r = 0; r < 4; r++) {
            float v = acc[r];
            int R = R0 + r;
            if (R < M) h1[(size_t)R * 128 + C] = f2bf(v);
            ss[r] = fmaf(v, as_, ss[r]);
            sd[r] = fmaf(v, ad_, sd[r]);
        }
    }
    // reduce over the 16 lanes sharing this row-quad (lane>>4 fixed)
    #pragma unroll
    for (int off = 1; off < 16; off <<= 1) {
        #pragma unroll
        for (int r = 0; r < 4; r++) {
            ss[r] += __shfl_xor(ss[r], off);
            sd[r] += __shfl_xor(sd[r], off);
        }
    }
    if ((lane & 15) == 0) {
        #pragma unroll
        for (int r = 0; r < 4; r++) {
            int R = R0 + r;
            if (R < M) { s_src[R] = ss[r]; s_dst[R] = sd[r]; }
        }
    }
}

// ---------------------------------------------------------------------------
// GEMM2: h2[M,40](bf16) = out1[M,128] @ W2, bf16 MFMA + fused scores.
// ---------------------------------------------------------------------------
__global__ __launch_bounds__(256) void gemm2_kernel(
    const float* __restrict__ out1, const short* __restrict__ bsw,
    const float* __restrict__ a_src, const float* __restrict__ a_dst,
    unsigned short* __restrict__ h2, float* __restrict__ s_src,
    float* __restrict__ s_dst, int M)
{
    __shared__ short xs[64][136];
    const int tid = threadIdx.x;
    const int rowBase = blockIdx.x * 64;

    #pragma unroll 4
    for (int i = 0; i < 8; i++) {
        int e = i * 1024 + tid * 4;
        int r = e >> 7, c = e & 127;
        int gr = rowBase + r;
        float4 v = make_float4(0.f, 0.f, 0.f, 0.f);
        if (gr < M) v = *(const float4*)(out1 + (size_t)gr * 128 + c);
        short4v s;
        s.x = (short)f2bf(v.x); s.y = (short)f2bf(v.y);
        s.z = (short)f2bf(v.z); s.w = (short)f2bf(v.w);
        *(short4v*)&xs[r][c] = s;
    }
    __syncthreads();

    const int wave = tid >> 6, lane = tid & 63;
    const int arow = wave * 16 + (lane & 15);
    const int acol0 = (lane >> 4) * 8;

    short8 a[4];
    #pragma unroll
    for (int k = 0; k < 4; k++)
        a[k] = *(const short8*)&xs[arow][k * 32 + acol0];

    const short8* __restrict__ bs = (const short8*)bsw;
    const int R0 = rowBase + wave * 16 + (lane >> 4) * 4;
    const int Cb = lane & 15;

    float ss[4] = {0.f, 0.f, 0.f, 0.f};
    float sd[4] = {0.f, 0.f, 0.f, 0.f};

    #pragma unroll
    for (int nt = 0; nt < 3; nt++) {
        f32x4 acc = {0.f, 0.f, 0.f, 0.f};
        #pragma unroll
        for (int k = 0; k < 4; k++) {
            short8 b = bs[(nt * 4 + k) * 64 + lane];
            acc = __builtin_amdgcn_mfma_f32_16x16x32_bf16(a[k], b, acc, 0, 0, 0);
        }
        int C = nt * 16 + Cb;
        bool valid = (C < 40);
        float as_ = valid ? a_src[C] : 0.f;
        float ad_ = valid ? a_dst[C] : 0.f;
        #pragma unroll
        for (int r = 0; r < 4; r++) {
            float v = acc[r];
            int R = R0 + r;
            if (valid && R < M) h2[(size_t)R * 40 + C] = f2bf(v);
            ss[r] = fmaf(v, as_, ss[r]);
            sd[r] = fmaf(v, ad_, sd[r]);
        }
    }
    #pragma unroll
    for (int off = 1; off < 16; off <<= 1) {
        #pragma unroll
        for (int r = 0; r < 4; r++) {
            ss[r] += __shfl_xor(ss[r], off);
            sd[r] += __shfl_xor(sd[r], off);
        }
    }
    if ((lane & 15) == 0) {
        #pragma unroll
        for (int r = 0; r < 4; r++) {
            int R = R0 + r;
            if (R < M) { s_src[R] = ss[r]; s_dst[R] = sd[r]; }
        }
    }
}

// ---------------------------------------------------------------------------
// CSR build: edges + self-loops in one pass (softmax is permutation-invariant
// within a dst segment, so interleaved order is fine).
// ---------------------------------------------------------------------------
__global__ void build_kernel(const int* __restrict__ ei, int* __restrict__ cnt,
                             int* __restrict__ csr, int E, int N)
{
    int i = blockIdx.x * blockDim.x + threadIdx.x;
    int s, d;
    if (i < E) { s = ei[i]; d = ei[E + i]; }
    else if (i < E + N) { s = d = i - E; }
    else return;
    int pos = atomicAdd(&cnt[d], 1);
    if (pos < CAP) csr[(size_t)d * CAP + pos] = s;
}

// ---------------------------------------------------------------------------
// GAT aggregation, bf16 features: one wave per dst node; lane j owns edge j.
// F==128: lane reads one dword = 2 bf16 (cols 2*lane, 2*lane+1).
// F==40: lanes 0..39 read one ushort.
// ---------------------------------------------------------------------------
template<int F, bool RELU, bool LOGSOFTMAX>
__global__ __launch_bounds__(256) void agg_kernel(
    const unsigned short* __restrict__ h, const int* __restrict__ csr,
    const int* __restrict__ cnt, const float* __restrict__ s_src,
    const float* __restrict__ s_dst, const float* __restrict__ bias,
    float* __restrict__ out, int N)
{
    int n = blockIdx.x * 4 + (threadIdx.x >> 6);
    if (n >= N) return;
    int lane = threadIdx.x & 63;
    int deg = cnt[n]; if (deg > CAP) deg = CAP;
    const int* __restrict__ edges = csr + (size_t)n * CAP;
    float sdn = s_dst[n];

    int   s_reg = (lane < deg) ? edges[lane] : 0;
    float e = (lane < deg) ? (s_src[s_reg] + sdn) : -1e30f;
    e = e > 0.f ? e : NEG_SLOPE * e;

    float m = e;
    #pragma unroll
    for (int off = 32; off; off >>= 1) m = fmaxf(m, __shfl_xor(m, off));

    float w_reg = (lane < deg) ? __expf(e - m) : 0.f;
    float denom = w_reg;
    #pragma unroll
    for (int off = 32; off; off >>= 1) denom += __shfl_xor(denom, off);
    float inv = 1.0f / denom;

    if (F == 128) {
        const unsigned* __restrict__ hp = (const unsigned*)h;  // row = 64 dwords
        float ax0 = 0.f, ay0 = 0.f, ax1 = 0.f, ay1 = 0.f;
        float ax2 = 0.f, ay2 = 0.f, ax3 = 0.f, ay3 = 0.f;
        int j = 0;
        for (; j + 3 < deg; j += 4) {
            int   s0 = __shfl(s_reg, j),     s1 = __shfl(s_reg, j + 1);
            int   s2 = __shfl(s_reg, j + 2), s3 = __shfl(s_reg, j + 3);
            float w0 = __shfl(w_reg, j),     w1 = __shfl(w_reg, j + 1);
            float w2 = __shfl(w_reg, j + 2), w3 = __shfl(w_reg, j + 3);
            unsigned u0 = hp[(size_t)s0 * 64 + lane];
            unsigned u1 = hp[(size_t)s1 * 64 + lane];
            unsigned u2 = hp[(size_t)s2 * 64 + lane];
            unsigned u3 = hp[(size_t)s3 * 64 + lane];
            ax0 = fmaf(w0, bfbits2f(u0 << 16), ax0); ay0 = fmaf(w0, bfbits2f(u0 & 0xFFFF0000u), ay0);
            ax1 = fmaf(w1, bfbits2f(u1 << 16), ax1); ay1 = fmaf(w1, bfbits2f(u1 & 0xFFFF0000u), ay1);
            ax2 = fmaf(w2, bfbits2f(u2 << 16), ax2); ay2 = fmaf(w2, bfbits2f(u2 & 0xFFFF0000u), ay2);
            ax3 = fmaf(w3, bfbits2f(u3 << 16), ax3); ay3 = fmaf(w3, bfbits2f(u3 & 0xFFFF0000u), ay3);
        }
        for (; j < deg; j++) {
            int   s0 = __shfl(s_reg, j);
            float w0 = __shfl(w_reg, j);
            unsigned u0 = hp[(size_t)s0 * 64 + lane];
            ax0 = fmaf(w0, bfbits2f(u0 << 16), ax0); ay0 = fmaf(w0, bfbits2f(u0 & 0xFFFF0000u), ay0);
        }
        float rx = (ax0 + ax1) + (ax2 + ax3);
        float ry = (ay0 + ay1) + (ay2 + ay3);
        rx = rx * inv + bias[2 * lane];
        ry = ry * inv + bias[2 * lane + 1];
        if (RELU) { rx = fmaxf(rx, 0.f); ry = fmaxf(ry, 0.f); }
        ((float2*)out)[(size_t)n * 64 + lane] = make_float2(rx, ry);
    } else {
        float acc0 = 0.f, acc1 = 0.f, acc2 = 0.f, acc3 = 0.f;
        int j = 0;
        for (; j + 3 < deg; j += 4) {
            int   s0 = __shfl(s_reg, j),     s1 = __shfl(s_reg, j + 1);
            int   s2 = __shfl(s_reg, j + 2), s3 = __shfl(s_reg, j + 3);
            float w0 = __shfl(w_reg, j),     w1 = __shfl(w_reg, j + 1);
            float w2 = __shfl(w_reg, j + 2), w3 = __shfl(w_reg, j + 3);
            float v0 = 0.f, v1 = 0.f, v2 = 0.f, v3 = 0.f;
            if (lane < F) {
                v0 = bfbits2f(((unsigned)h[(size_t)s0 * F + lane]) << 16);
                v1 = bfbits2f(((unsigned)h[(size_t)s1 * F + lane]) << 16);
                v2 = bfbits2f(((unsigned)h[(size_t)s2 * F + lane]) << 16);
                v3 = bfbits2f(((unsigned)h[(size_t)s3 * F + lane]) << 16);
            }
            acc0 = fmaf(w0, v0, acc0);
            acc1 = fmaf(w1, v1, acc1);
            acc2 = fmaf(w2, v2, acc2);
            acc3 = fmaf(w3, v3, acc3);
        }
        for (; j < deg; j++) {
            int   s0 = __shfl(s_reg, j);
            float w0 = __shfl(w_reg, j);
            float v0 = (lane < F) ? bfbits2f(((unsigned)h[(size_t)s0 * F + lane]) << 16) : 0.f;
            acc0 = fmaf(w0, v0, acc0);
        }
        float v = (acc0 + acc1) + (acc2 + acc3);
        v = (lane < F) ? (v * inv + bias[lane]) : -1e30f;
        if (LOGSOFTMAX) {
            float mx = v;
            #pragma unroll
            for (int off = 32; off; off >>= 1) mx = fmaxf(mx, __shfl_xor(mx, off));
            float ex = (lane < F) ? __expf(v - mx) : 0.f;
            float sum = ex;
            #pragma unroll
            for (int off = 32; off; off >>= 1) sum += __shfl_xor(sum, off);
            v = v - mx - __logf(sum);
        }
        if (lane < F) out[(size_t)n * F + lane] = v;
    }
}

// ---------------------------------------------------------------------------
extern "C" void kernel_launch(void* const* d_in, const int* in_sizes, int n_in,
                              void* d_out, int out_size, void* d_ws, size_t ws_size,
                              hipStream_t stream)
{
    const float* x      = (const float*)d_in[0];   // [N, 256]
    const int*   ei     = (const int*)d_in[1];     // [2, E]
    const float* W1     = (const float*)d_in[2];   // [256, 128]
    const float* a_src1 = (const float*)d_in[3];
    const float* a_dst1 = (const float*)d_in[4];
    const float* b1     = (const float*)d_in[5];
    const float* W2     = (const float*)d_in[6];   // [128, 40]
    const float* a_src2 = (const float*)d_in[7];
    const float* a_dst2 = (const float*)d_in[8];
    const float* b2     = (const float*)d_in[9];
    float* out = (float*)d_out;                    // [N, 40]

    const int N = 100000;
    const int E = 1600000;

    char* ws = (char*)d_ws;
    size_t off = 0;
    auto alloc = [&](size_t bytes) -> void* {
        void* p = ws + off;
        off += (bytes + 255) & ~(size_t)255;
        return p;
    };
    unsigned short* h1b = (unsigned short*)alloc((size_t)N * 128 * 2); // bf16
    float* out1 = (float*)alloc((size_t)N * 128 * 4);
    unsigned short* h2b = (unsigned short*)alloc((size_t)N * 40 * 2);  // bf16
    int*   csr  = (int*)alloc((size_t)N * CAP * 4);
    int*   cnt  = (int*)alloc((size_t)N * 4);
    float* ss1  = (float*)alloc((size_t)N * 4);
    float* sd1  = (float*)alloc((size_t)N * 4);
    float* ss2  = (float*)alloc((size_t)N * 4);
    float* sd2  = (float*)alloc((size_t)N * 4);
    short* bsw1 = (short*)alloc((size_t)4096 * 8 * 2);
    short* bsw2 = (short*)alloc((size_t)768 * 8 * 2);

    hipMemsetAsync(cnt, 0, (size_t)N * 4, stream);

    build_kernel<<<dim3((E + N + 255) / 256), dim3(256), 0, stream>>>(ei, cnt, csr, E, N);
    pack_w1_kernel<<<dim3(16), dim3(256), 0, stream>>>(W1, bsw1);
    pack_w2_kernel<<<dim3(3), dim3(256), 0, stream>>>(W2, bsw2);

    // ----- layer 1 -----
    gemm1_kernel<<<dim3((N + 63) / 64), dim3(256), 0, stream>>>(
        x, bsw1, a_src1, a_dst1, h1b, ss1, sd1, N);
    agg_kernel<128, true, false><<<dim3((N + 3) / 4), dim3(256), 0, stream>>>(
        h1b, csr, cnt, ss1, sd1, b1, out1, N);

    // ----- layer 2 -----
    gemm2_kernel<<<dim3((N + 63) / 64), dim3(256), 0, stream>>>(
        out1, bsw2, a_src2, a_dst2, h2b, ss2, sd2, N);
    agg_kernel<40, false, true><<<dim3((N + 3) / 4), dim3(256), 0, stream>>>(
        h2b, csr, cnt, ss2, sd2, b2, out, N);
}